// Round 1
// baseline (523.873 us; speedup 1.0000x reference)
//
#include <hip/hip_runtime.h>
#include <cmath>

#define BB 8192
#define NCH 64           // row chunks for column-direction kernels

static constexpr float kG1 = 10.0f;
static constexpr float kG2 = 0.5f;
static constexpr float kDelta = 0.2f;

__device__ __forceinline__ float wsum(float v){
#pragma unroll
  for (int o = 32; o > 0; o >>= 1) v += __shfl_xor(v, o);
  return v;
}
__device__ __forceinline__ float wmaxr(float v){
#pragma unroll
  for (int o = 32; o > 0; o >>= 1) v = fmaxf(v, __shfl_xor(v, o));
  return v;
}
__device__ __forceinline__ float wminr(float v){
#pragma unroll
  for (int o = 32; o > 0; o >>= 1) v = fminf(v, __shfl_xor(v, o));
  return v;
}

// ws layout (ints/floats):
//   [0,   BB)  row_max_an  (float bits as int)
//   [BB, 2BB)  col_max_an
//   [2BB,3BB)  row_min_ap
//   [3BB,4BB)  col_min_ap
//   [4BB,5BB)  row_pos  (float)
//   [5BB,6BB)  row_neg
//   [6BB,7BB)  col_pos
//   [7BB,8BB)  col_neg

__global__ __launch_bounds__(256) void k_init(int* __restrict__ wsi, float* __restrict__ out){
  int i = blockIdx.x * 256 + threadIdx.x;
  if (i < 2*BB)      wsi[i] = (int)0xFF800000u;   // -inf
  else if (i < 4*BB) wsi[i] = 0x7F800000;         // +inf
  else if (i < 8*BB) reinterpret_cast<float*>(wsi)[i] = 0.0f;
  if (i == 0) out[0] = 0.0f;
}

__global__ __launch_bounds__(256) void k_row_stats(const float* __restrict__ S,
                                                   const int* __restrict__ tg,
                                                   int* __restrict__ row_max,
                                                   int* __restrict__ row_min){
  const int r = blockIdx.x;
  const int tr = tg[r];
  const float4* row = reinterpret_cast<const float4*>(S + (size_t)r * BB);
  const int4*  t4  = reinterpret_cast<const int4*>(tg);
  float mx = -INFINITY, mn = INFINITY;
  for (int it = threadIdx.x; it < BB/4; it += 256){
    float4 v = row[it];
    int4   t = t4[it];
    if (t.x == tr) mn = fminf(mn, v.x); else mx = fmaxf(mx, v.x);
    if (t.y == tr) mn = fminf(mn, v.y); else mx = fmaxf(mx, v.y);
    if (t.z == tr) mn = fminf(mn, v.z); else mx = fmaxf(mx, v.z);
    if (t.w == tr) mn = fminf(mn, v.w); else mx = fmaxf(mx, v.w);
  }
  mx = wmaxr(mx); mn = wminr(mn);
  __shared__ float smx[4], smn[4];
  const int wid = threadIdx.x >> 6;
  if ((threadIdx.x & 63) == 0){ smx[wid] = mx; smn[wid] = mn; }
  __syncthreads();
  if (threadIdx.x == 0){
    float a = smx[0], b = smn[0];
#pragma unroll
    for (int w = 1; w < 4; ++w){ a = fmaxf(a, smx[w]); b = fminf(b, smn[w]); }
    row_max[r] = __float_as_int(a);
    row_min[r] = __float_as_int(b);
  }
}

__global__ __launch_bounds__(256) void k_row_sums(const float* __restrict__ S,
                                                  const int* __restrict__ tg,
                                                  const int* __restrict__ row_max,
                                                  const int* __restrict__ row_min,
                                                  float* __restrict__ row_pos,
                                                  float* __restrict__ row_neg){
  const int r = blockIdx.x;
  const int tr = tg[r];
  const float pth = __int_as_float(row_max[r]) + kDelta;   // S < pth for positives
  const float nth = __int_as_float(row_min[r]) - kDelta;   // S > nth for negatives
  const float4* row = reinterpret_cast<const float4*>(S + (size_t)r * BB);
  const int4*  t4  = reinterpret_cast<const int4*>(tg);
  float pos = 0.f, neg = 0.f;
  for (int it = threadIdx.x; it < BB/4; it += 256){
    float4 v = row[it];
    int4   t = t4[it];
    if (t.x == tr){ if (v.x < pth) pos += __expf(kG2 - kG1 * v.x); }
    else          { if (v.x > nth) neg += __expf(kG1 * v.x - kG2); }
    if (t.y == tr){ if (v.y < pth) pos += __expf(kG2 - kG1 * v.y); }
    else          { if (v.y > nth) neg += __expf(kG1 * v.y - kG2); }
    if (t.z == tr){ if (v.z < pth) pos += __expf(kG2 - kG1 * v.z); }
    else          { if (v.z > nth) neg += __expf(kG1 * v.z - kG2); }
    if (t.w == tr){ if (v.w < pth) pos += __expf(kG2 - kG1 * v.w); }
    else          { if (v.w > nth) neg += __expf(kG1 * v.w - kG2); }
  }
  pos = wsum(pos); neg = wsum(neg);
  __shared__ float sp[4], sn[4];
  const int wid = threadIdx.x >> 6;
  if ((threadIdx.x & 63) == 0){ sp[wid] = pos; sn[wid] = neg; }
  __syncthreads();
  if (threadIdx.x == 0){
    float a = sp[0], b = sn[0];
#pragma unroll
    for (int w = 1; w < 4; ++w){ a += sp[w]; b += sn[w]; }
    row_pos[r] = a; row_neg[r] = b;
  }
}

__global__ __launch_bounds__(256) void k_col_stats(const float* __restrict__ S,
                                                   const int* __restrict__ tg,
                                                   int* __restrict__ col_max,
                                                   int* __restrict__ col_min){
  const int c = (blockIdx.x * 256 + threadIdx.x) * 4;
  const int4 tc = *reinterpret_cast<const int4*>(tg + c);
  const int r0 = blockIdx.y * (BB / NCH);
  const int r1 = r0 + (BB / NCH);
  float mx0=-INFINITY, mx1=-INFINITY, mx2=-INFINITY, mx3=-INFINITY;
  float mn0= INFINITY, mn1= INFINITY, mn2= INFINITY, mn3= INFINITY;
  for (int i = r0; i < r1; ++i){
    float4 v = *reinterpret_cast<const float4*>(S + (size_t)i * BB + c);
    const int ti = tg[i];
    if (ti == tc.x) mn0 = fminf(mn0, v.x); else mx0 = fmaxf(mx0, v.x);
    if (ti == tc.y) mn1 = fminf(mn1, v.y); else mx1 = fmaxf(mx1, v.y);
    if (ti == tc.z) mn2 = fminf(mn2, v.z); else mx2 = fmaxf(mx2, v.z);
    if (ti == tc.w) mn3 = fminf(mn3, v.w); else mx3 = fmaxf(mx3, v.w);
  }
  atomicMax(col_max + c + 0, __float_as_int(mx0));
  atomicMax(col_max + c + 1, __float_as_int(mx1));
  atomicMax(col_max + c + 2, __float_as_int(mx2));
  atomicMax(col_max + c + 3, __float_as_int(mx3));
  atomicMin(col_min + c + 0, __float_as_int(mn0));
  atomicMin(col_min + c + 1, __float_as_int(mn1));
  atomicMin(col_min + c + 2, __float_as_int(mn2));
  atomicMin(col_min + c + 3, __float_as_int(mn3));
}

__global__ __launch_bounds__(256) void k_col_sums(const float* __restrict__ S,
                                                  const int* __restrict__ tg,
                                                  const int* __restrict__ col_max,
                                                  const int* __restrict__ col_min,
                                                  float* __restrict__ col_pos,
                                                  float* __restrict__ col_neg){
  const int c = (blockIdx.x * 256 + threadIdx.x) * 4;
  const int4 tc = *reinterpret_cast<const int4*>(tg + c);
  const float pth0 = __int_as_float(col_max[c+0]) + kDelta;
  const float pth1 = __int_as_float(col_max[c+1]) + kDelta;
  const float pth2 = __int_as_float(col_max[c+2]) + kDelta;
  const float pth3 = __int_as_float(col_max[c+3]) + kDelta;
  const float nth0 = __int_as_float(col_min[c+0]) - kDelta;
  const float nth1 = __int_as_float(col_min[c+1]) - kDelta;
  const float nth2 = __int_as_float(col_min[c+2]) - kDelta;
  const float nth3 = __int_as_float(col_min[c+3]) - kDelta;
  const int r0 = blockIdx.y * (BB / NCH);
  const int r1 = r0 + (BB / NCH);
  float p0=0.f,p1=0.f,p2=0.f,p3=0.f, n0=0.f,n1=0.f,n2=0.f,n3=0.f;
  for (int i = r0; i < r1; ++i){
    float4 v = *reinterpret_cast<const float4*>(S + (size_t)i * BB + c);
    const int ti = tg[i];
    if (ti == tc.x){ if (v.x < pth0) p0 += __expf(kG2 - kG1 * v.x); }
    else           { if (v.x > nth0) n0 += __expf(kG1 * v.x - kG2); }
    if (ti == tc.y){ if (v.y < pth1) p1 += __expf(kG2 - kG1 * v.y); }
    else           { if (v.y > nth1) n1 += __expf(kG1 * v.y - kG2); }
    if (ti == tc.z){ if (v.z < pth2) p2 += __expf(kG2 - kG1 * v.z); }
    else           { if (v.z > nth2) n2 += __expf(kG1 * v.z - kG2); }
    if (ti == tc.w){ if (v.w < pth3) p3 += __expf(kG2 - kG1 * v.w); }
    else           { if (v.w > nth3) n3 += __expf(kG1 * v.w - kG2); }
  }
  atomicAdd(col_pos + c + 0, p0);
  atomicAdd(col_pos + c + 1, p1);
  atomicAdd(col_pos + c + 2, p2);
  atomicAdd(col_pos + c + 3, p3);
  atomicAdd(col_neg + c + 0, n0);
  atomicAdd(col_neg + c + 1, n1);
  atomicAdd(col_neg + c + 2, n2);
  atomicAdd(col_neg + c + 3, n3);
}

__global__ __launch_bounds__(256) void k_final(const float* __restrict__ row_pos,
                                               const float* __restrict__ row_neg,
                                               const float* __restrict__ col_pos,
                                               const float* __restrict__ col_neg,
                                               float* __restrict__ out){
  const int r = blockIdx.x * 256 + threadIdx.x;
  const float rp = row_pos[r], rn = row_neg[r];
  const float cp = col_pos[r], cn = col_neg[r];
  float l = 0.f;
  if (rp > 0.f && rn > 0.f && cp > 0.f && cn > 0.f)
    l = (logf(rp) + logf(rn) + logf(cp) + logf(cn)) * (1.0f / kG1);
  l = wsum(l);
  __shared__ float sm[4];
  const int wid = threadIdx.x >> 6;
  if ((threadIdx.x & 63) == 0) sm[wid] = l;
  __syncthreads();
  if (threadIdx.x == 0){
    float a = sm[0] + sm[1] + sm[2] + sm[3];
    atomicAdd(out, a * (1.0f / (float)BB));
  }
}

extern "C" void kernel_launch(void* const* d_in, const int* in_sizes, int n_in,
                              void* d_out, int out_size, void* d_ws, size_t ws_size,
                              hipStream_t stream) {
  const float* S  = (const float*)d_in[0];
  const int*   tg = (const int*)d_in[1];
  int*   wsi = (int*)d_ws;
  float* wsf = (float*)d_ws;
  int* row_max = wsi;
  int* col_max = wsi + BB;
  int* row_min = wsi + 2*BB;
  int* col_min = wsi + 3*BB;
  float* row_pos = wsf + 4*BB;
  float* row_neg = wsf + 5*BB;
  float* col_pos = wsf + 6*BB;
  float* col_neg = wsf + 7*BB;
  float* out = (float*)d_out;

  k_init<<<(8*BB)/256, 256, 0, stream>>>(wsi, out);
  k_row_stats<<<BB, 256, 0, stream>>>(S, tg, row_max, row_min);
  k_col_stats<<<dim3(BB/1024, NCH), 256, 0, stream>>>(S, tg, col_max, col_min);
  k_row_sums<<<BB, 256, 0, stream>>>(S, tg, row_max, row_min, row_pos, row_neg);
  k_col_sums<<<dim3(BB/1024, NCH), 256, 0, stream>>>(S, tg, col_max, col_min, col_pos, col_neg);
  k_final<<<BB/256, 256, 0, stream>>>(row_pos, row_neg, col_pos, col_neg, out);
}

// Round 2
// 476.869 us; speedup vs baseline: 1.0986x; 1.0986x over previous
//
#include <hip/hip_runtime.h>
#include <cmath>

#define BB 8192
#define RPB 64                 // rows per block (chunk)
#define GY (BB / RPB)          // 128 row-chunks
#define GX (BB / 1024)         // 8 col-blocks (256 threads * 4 cols)

static constexpr float kG1 = 10.0f;
static constexpr float kG2 = 0.5f;
static constexpr float kDelta = 0.2f;

__device__ __forceinline__ float wsum(float v){
#pragma unroll
  for (int o = 32; o > 0; o >>= 1) v += __shfl_xor(v, o);
  return v;
}

// ws layout:
//   [0,   BB)  row_max_an  (float bits as int, init -inf)
//   [BB, 2BB)  col_max_an
//   [2BB,3BB)  row_min_ap  (init +inf)
//   [3BB,4BB)  col_min_ap
//   [4BB,5BB)  row_pos  (float, init 0)
//   [5BB,6BB)  row_neg
//   [6BB,7BB)  col_pos
//   [7BB,8BB)  col_neg

__global__ __launch_bounds__(256) void k_init(int* __restrict__ wsi, float* __restrict__ out){
  int i = blockIdx.x * 256 + threadIdx.x;
  if (i < 2*BB)      wsi[i] = (int)0xFF800000u;   // -inf
  else if (i < 4*BB) wsi[i] = 0x7F800000;         // +inf
  else if (i < 8*BB) reinterpret_cast<float*>(wsi)[i] = 0.0f;
  if (i == 0) out[0] = 0.0f;
}

// Pass A: one sweep -> row max_an / min_ap AND col max_an / min_ap
__global__ __launch_bounds__(256) void k_stats(const float* __restrict__ S,
                                               const int* __restrict__ tg,
                                               int* __restrict__ row_max,
                                               int* __restrict__ row_min,
                                               int* __restrict__ col_max,
                                               int* __restrict__ col_min){
  const int c = (blockIdx.x * 256 + threadIdx.x) * 4;
  const int4 tc = *reinterpret_cast<const int4*>(tg + c);
  const int r0 = blockIdx.y * RPB;
  const int lane = threadIdx.x & 63;

  float cmx0=-INFINITY, cmx1=-INFINITY, cmx2=-INFINITY, cmx3=-INFINITY;
  float cmn0= INFINITY, cmn1= INFINITY, cmn2= INFINITY, cmn3= INFINITY;

  __shared__ int s_t[RPB];
  if (threadIdx.x < RPB) s_t[threadIdx.x] = tg[r0 + threadIdx.x];
  __syncthreads();

#pragma unroll 2
  for (int k = 0; k < RPB; ++k){
    const int i = r0 + k;
    const float4 v = *reinterpret_cast<const float4*>(S + (size_t)i * BB + c);
    const int ti = s_t[k];
    float rmx = -INFINITY, rmn = INFINITY;
    if (ti == tc.x){ cmn0 = fminf(cmn0, v.x); rmn = fminf(rmn, v.x); }
    else           { cmx0 = fmaxf(cmx0, v.x); rmx = fmaxf(rmx, v.x); }
    if (ti == tc.y){ cmn1 = fminf(cmn1, v.y); rmn = fminf(rmn, v.y); }
    else           { cmx1 = fmaxf(cmx1, v.y); rmx = fmaxf(rmx, v.y); }
    if (ti == tc.z){ cmn2 = fminf(cmn2, v.z); rmn = fminf(rmn, v.z); }
    else           { cmx2 = fmaxf(cmx2, v.z); rmx = fmaxf(rmx, v.z); }
    if (ti == tc.w){ cmn3 = fminf(cmn3, v.w); rmn = fminf(rmn, v.w); }
    else           { cmx3 = fmaxf(cmx3, v.w); rmx = fmaxf(rmx, v.w); }
#pragma unroll
    for (int o = 32; o > 0; o >>= 1){
      rmx = fmaxf(rmx, __shfl_xor(rmx, o));
      rmn = fminf(rmn, __shfl_xor(rmn, o));
    }
    if (lane == 0){
      atomicMax(row_max + i, __float_as_int(rmx));
      atomicMin(row_min + i, __float_as_int(rmn));
    }
  }
  atomicMax(col_max + c + 0, __float_as_int(cmx0));
  atomicMax(col_max + c + 1, __float_as_int(cmx1));
  atomicMax(col_max + c + 2, __float_as_int(cmx2));
  atomicMax(col_max + c + 3, __float_as_int(cmx3));
  atomicMin(col_min + c + 0, __float_as_int(cmn0));
  atomicMin(col_min + c + 1, __float_as_int(cmn1));
  atomicMin(col_min + c + 2, __float_as_int(cmn2));
  atomicMin(col_min + c + 3, __float_as_int(cmn3));
}

// Pass B: one sweep -> row pos/neg exp-sums AND col pos/neg exp-sums
__global__ __launch_bounds__(256) void k_sums(const float* __restrict__ S,
                                              const int* __restrict__ tg,
                                              const int* __restrict__ row_max,
                                              const int* __restrict__ row_min,
                                              const int* __restrict__ col_max,
                                              const int* __restrict__ col_min,
                                              float* __restrict__ row_pos,
                                              float* __restrict__ row_neg,
                                              float* __restrict__ col_pos,
                                              float* __restrict__ col_neg){
  const int c = (blockIdx.x * 256 + threadIdx.x) * 4;
  const int4 tc = *reinterpret_cast<const int4*>(tg + c);
  const int r0 = blockIdx.y * RPB;
  const int lane = threadIdx.x & 63;

  const float cpth0 = __int_as_float(col_max[c+0]) + kDelta;
  const float cpth1 = __int_as_float(col_max[c+1]) + kDelta;
  const float cpth2 = __int_as_float(col_max[c+2]) + kDelta;
  const float cpth3 = __int_as_float(col_max[c+3]) + kDelta;
  const float cnth0 = __int_as_float(col_min[c+0]) - kDelta;
  const float cnth1 = __int_as_float(col_min[c+1]) - kDelta;
  const float cnth2 = __int_as_float(col_min[c+2]) - kDelta;
  const float cnth3 = __int_as_float(col_min[c+3]) - kDelta;

  __shared__ int   s_t[RPB];
  __shared__ float s_pth[RPB], s_nth[RPB];
  if (threadIdx.x < RPB){
    const int i = r0 + threadIdx.x;
    s_t[threadIdx.x]   = tg[i];
    s_pth[threadIdx.x] = __int_as_float(row_max[i]) + kDelta;
    s_nth[threadIdx.x] = __int_as_float(row_min[i]) - kDelta;
  }
  __syncthreads();

  float cp0=0.f,cp1=0.f,cp2=0.f,cp3=0.f, cn0=0.f,cn1=0.f,cn2=0.f,cn3=0.f;

#pragma unroll 2
  for (int k = 0; k < RPB; ++k){
    const int i = r0 + k;
    const float4 v = *reinterpret_cast<const float4*>(S + (size_t)i * BB + c);
    const int   ti  = s_t[k];
    const float rpth = s_pth[k], rnth = s_nth[k];
    float rp = 0.f, rn = 0.f;

    {
      const bool pos = (ti == tc.x);
      const float arg = kG1 * v.x - kG2;
      const float e = __expf(pos ? -arg : arg);
      if (pos){ if (v.x < rpth) rp += e;  if (v.x < cpth0) cp0 += e; }
      else    { if (v.x > rnth) rn += e;  if (v.x > cnth0) cn0 += e; }
    }
    {
      const bool pos = (ti == tc.y);
      const float arg = kG1 * v.y - kG2;
      const float e = __expf(pos ? -arg : arg);
      if (pos){ if (v.y < rpth) rp += e;  if (v.y < cpth1) cp1 += e; }
      else    { if (v.y > rnth) rn += e;  if (v.y > cnth1) cn1 += e; }
    }
    {
      const bool pos = (ti == tc.z);
      const float arg = kG1 * v.z - kG2;
      const float e = __expf(pos ? -arg : arg);
      if (pos){ if (v.z < rpth) rp += e;  if (v.z < cpth2) cp2 += e; }
      else    { if (v.z > rnth) rn += e;  if (v.z > cnth2) cn2 += e; }
    }
    {
      const bool pos = (ti == tc.w);
      const float arg = kG1 * v.w - kG2;
      const float e = __expf(pos ? -arg : arg);
      if (pos){ if (v.w < rpth) rp += e;  if (v.w < cpth3) cp3 += e; }
      else    { if (v.w > rnth) rn += e;  if (v.w > cnth3) cn3 += e; }
    }

    rp = wsum(rp); rn = wsum(rn);
    if (lane == 0){
      atomicAdd(row_pos + i, rp);
      atomicAdd(row_neg + i, rn);
    }
  }
  atomicAdd(col_pos + c + 0, cp0);
  atomicAdd(col_pos + c + 1, cp1);
  atomicAdd(col_pos + c + 2, cp2);
  atomicAdd(col_pos + c + 3, cp3);
  atomicAdd(col_neg + c + 0, cn0);
  atomicAdd(col_neg + c + 1, cn1);
  atomicAdd(col_neg + c + 2, cn2);
  atomicAdd(col_neg + c + 3, cn3);
}

__global__ __launch_bounds__(256) void k_final(const float* __restrict__ row_pos,
                                               const float* __restrict__ row_neg,
                                               const float* __restrict__ col_pos,
                                               const float* __restrict__ col_neg,
                                               float* __restrict__ out){
  const int r = blockIdx.x * 256 + threadIdx.x;
  const float rp = row_pos[r], rn = row_neg[r];
  const float cp = col_pos[r], cn = col_neg[r];
  float l = 0.f;
  if (rp > 0.f && rn > 0.f && cp > 0.f && cn > 0.f)
    l = (logf(rp) + logf(rn) + logf(cp) + logf(cn)) * (1.0f / kG1);
  l = wsum(l);
  __shared__ float sm[4];
  const int wid = threadIdx.x >> 6;
  if ((threadIdx.x & 63) == 0) sm[wid] = l;
  __syncthreads();
  if (threadIdx.x == 0){
    float a = sm[0] + sm[1] + sm[2] + sm[3];
    atomicAdd(out, a * (1.0f / (float)BB));
  }
}

extern "C" void kernel_launch(void* const* d_in, const int* in_sizes, int n_in,
                              void* d_out, int out_size, void* d_ws, size_t ws_size,
                              hipStream_t stream) {
  const float* S  = (const float*)d_in[0];
  const int*   tg = (const int*)d_in[1];
  int*   wsi = (int*)d_ws;
  float* wsf = (float*)d_ws;
  int* row_max = wsi;
  int* col_max = wsi + BB;
  int* row_min = wsi + 2*BB;
  int* col_min = wsi + 3*BB;
  float* row_pos = wsf + 4*BB;
  float* row_neg = wsf + 5*BB;
  float* col_pos = wsf + 6*BB;
  float* col_neg = wsf + 7*BB;
  float* out = (float*)d_out;

  k_init<<<(8*BB)/256, 256, 0, stream>>>(wsi, out);
  k_stats<<<dim3(GX, GY), 256, 0, stream>>>(S, tg, row_max, row_min, col_max, col_min);
  k_sums <<<dim3(GX, GY), 256, 0, stream>>>(S, tg, row_max, row_min, col_max, col_min,
                                            row_pos, row_neg, col_pos, col_neg);
  k_final<<<BB/256, 256, 0, stream>>>(row_pos, row_neg, col_pos, col_neg, out);
}